// Round 2
// baseline (515.324 us; speedup 1.0000x reference)
//
#include <hip/hip_runtime.h>

// ---------- common helpers ----------
typedef short bf16x8 __attribute__((ext_vector_type(8)));
typedef float f32x4 __attribute__((ext_vector_type(4)));

__device__ __forceinline__ void async16(const void* g, const void* l) {
  __builtin_amdgcn_global_load_lds(
      (const __attribute__((address_space(1))) unsigned int*)g,
      (__attribute__((address_space(3))) unsigned int*)(void*)(uintptr_t)l,
      16, 0, 0);
}

__device__ __forceinline__ unsigned short f2b(float f) {
  unsigned int u = __float_as_uint(f);
  u += 0x7fffu + ((u >> 16) & 1u);   // round-to-nearest-even
  return (unsigned short)(u >> 16);
}

// ---------- cast fp32 -> bf16, n % 1024 == 0 ----------
__global__ __launch_bounds__(256) void cast_f32_bf16(
    const float* __restrict__ in, unsigned short* __restrict__ out, int n) {
  int i = (blockIdx.x * 256 + threadIdx.x) * 4;
  if (i < n) {
    float4 v = *(const float4*)(in + i);
    ushort4 o;
    o.x = f2b(v.x); o.y = f2b(v.y); o.z = f2b(v.z); o.w = f2b(v.w);
    *(ushort4*)(out + i) = o;
  }
}

// ---------- transpose+cast: out_bf16[N][K] = in_f32[K][N], K,N multiples of 64 ----------
__global__ __launch_bounds__(256) void transpose_cast(
    const float* __restrict__ in, unsigned short* __restrict__ out,
    int K, int N) {
  __shared__ __align__(16) unsigned short tile[64][65];
  const int k0 = blockIdx.y * 64, n0 = blockIdx.x * 64;
  const int tid = threadIdx.x;
  const int r = tid >> 4, c4 = tid & 15;
#pragma unroll
  for (int p = 0; p < 4; ++p) {
    int row = p * 16 + r;
    float4 v = *(const float4*)(in + (size_t)(k0 + row) * N + n0 + c4 * 4);
    tile[c4 * 4 + 0][row] = f2b(v.x);
    tile[c4 * 4 + 1][row] = f2b(v.y);
    tile[c4 * 4 + 2][row] = f2b(v.z);
    tile[c4 * 4 + 3][row] = f2b(v.w);
  }
  __syncthreads();
#pragma unroll
  for (int p = 0; p < 4; ++p) {
    int nr = p * 16 + r;
    ushort4 o;
    o.x = tile[nr][c4 * 4 + 0];
    o.y = tile[nr][c4 * 4 + 1];
    o.z = tile[nr][c4 * 4 + 2];
    o.w = tile[nr][c4 * 4 + 3];
    *(ushort4*)(out + (size_t)(n0 + nr) * K + k0 + c4 * 4) = o;
  }
}

// ---------- transpose bf16: out[N][K] = in[K][N], K,N multiples of 64 ----------
__global__ __launch_bounds__(256) void transpose_bf16(
    const unsigned short* __restrict__ in, unsigned short* __restrict__ out,
    int K, int N) {
  __shared__ __align__(16) unsigned short tile[64][65];
  const int k0 = blockIdx.y * 64, n0 = blockIdx.x * 64;
  const int tid = threadIdx.x;
  const int r = tid >> 4, c4 = tid & 15;
#pragma unroll
  for (int p = 0; p < 4; ++p) {
    int row = p * 16 + r;
    ushort4 v = *(const ushort4*)(in + (size_t)(k0 + row) * N + n0 + c4 * 4);
    tile[c4 * 4 + 0][row] = v.x;
    tile[c4 * 4 + 1][row] = v.y;
    tile[c4 * 4 + 2][row] = v.z;
    tile[c4 * 4 + 3][row] = v.w;
  }
  __syncthreads();
#pragma unroll
  for (int p = 0; p < 4; ++p) {
    int nr = p * 16 + r;
    ushort4 o;
    o.x = tile[nr][c4 * 4 + 0];
    o.y = tile[nr][c4 * 4 + 1];
    o.z = tile[nr][c4 * 4 + 2];
    o.w = tile[nr][c4 * 4 + 3];
    *(ushort4*)(out + (size_t)(n0 + nr) * K + k0 + c4 * 4) = o;
  }
}

// ---------- GEMM: C[M,N] = A[M,K] @ BT[N,K]^T (bf16 in, fp32 accum) ----------
// M%128==0, N%128==0, K%64==0. m97-style: 128x128 tile, BK=64, 4 waves 2x2.
// cscale multiplies the bf16 (Cb) output only (used to pre-scale Q by
// 1/sqrt(Dh)*log2e so attention's softmax has no per-score multiply).
__global__ __launch_bounds__(256) void gemm_bt(
    const unsigned short* __restrict__ A, const unsigned short* __restrict__ BT,
    unsigned short* __restrict__ Cb, float* __restrict__ Cf, int M, int N, int K,
    float cscale) {
  __shared__ __align__(16) unsigned short sA[128 * 64];
  __shared__ __align__(16) unsigned short sB[128 * 64];
  const int tid = threadIdx.x;
  const int wave = tid >> 6, lane = tid & 63;
  const int quad = lane >> 4, cl = lane & 15;
  const int m0 = blockIdx.y * 128, n0 = blockIdx.x * 128;
  const int wm = (wave >> 1) * 64, wn = (wave & 1) * 64;
  (void)M;

  f32x4 acc[4][4] = {};

  const unsigned short* gA = A + (size_t)(m0 + wave * 32 + (lane >> 3)) * K + (lane & 7) * 8;
  const unsigned short* gB = BT + (size_t)(n0 + wave * 32 + (lane >> 3)) * K + (lane & 7) * 8;
  char* lA = (char*)sA + (wave * 32) * 128;
  char* lB = (char*)sB + (wave * 32) * 128;

  for (int kt = 0; kt < K; kt += 64) {
#pragma unroll
    for (int r = 0; r < 4; ++r) {
      async16(gA + (size_t)r * 8 * K + kt, lA + r * 8 * 128);
      async16(gB + (size_t)r * 8 * K + kt, lB + r * 8 * 128);
    }
    __syncthreads();
#pragma unroll
    for (int kk = 0; kk < 64; kk += 32) {
      bf16x8 af[4], bfr[4];
#pragma unroll
      for (int i = 0; i < 4; ++i)
        af[i] = *(const bf16x8*)((const char*)sA + (wm + i * 16 + cl) * 128 + kk * 2 + quad * 16);
#pragma unroll
      for (int j = 0; j < 4; ++j)
        bfr[j] = *(const bf16x8*)((const char*)sB + (wn + j * 16 + cl) * 128 + kk * 2 + quad * 16);
#pragma unroll
      for (int i = 0; i < 4; ++i)
#pragma unroll
        for (int j = 0; j < 4; ++j)
          acc[i][j] = __builtin_amdgcn_mfma_f32_16x16x32_bf16(af[i], bfr[j], acc[i][j], 0, 0, 0);
    }
    __syncthreads();
  }
#pragma unroll
  for (int i = 0; i < 4; ++i)
#pragma unroll
    for (int j = 0; j < 4; ++j)
#pragma unroll
      for (int r = 0; r < 4; ++r) {
        int row = m0 + wm + i * 16 + quad * 4 + r;
        int col = n0 + wn + j * 16 + cl;
        float v = acc[i][j][r];
        if (Cb) Cb[(size_t)row * N + col] = f2b(v * cscale);
        if (Cf) Cf[(size_t)row * N + col] = v;
      }
}

// ---------- flash-style causal attention, v5 ----------
// grid: (T/64, H, B) = (32,16,2) = 1024 blocks, 256 threads. ONE 64-row
// q-tile per block (v3's paired structure capped the grid at 512 blocks =
// 2 blocks/CU; the kernel is latency-bound, so resident-block overlap is
// the lever). Heavy-first: qt = 31 - bx so 32-k-tile blocks dispatch first
// and the tail is 1-tile blocks. LDS 40KB + VGPR<=128 (__launch_bounds__
// (256,4)) -> up to 4 blocks/CU. Single-buffer staging (v3-proven); v4's
// 72KB double-buffer dropped residency to 1 block/CU and regressed 1.75x.
// Kept from v4: defer-max rescale skip; softmax scale pre-folded into Q.
__global__ __launch_bounds__(256, 4) void mla_attn(
    const unsigned short* __restrict__ Qm, const unsigned short* __restrict__ Km,
    const unsigned short* __restrict__ Vt, unsigned short* __restrict__ Om, int T) {
  const int ld = 2048;
  const int ldv = 4096;  // B*T
  __shared__ __align__(16) unsigned short sK[64 * 128];   // [t][d] xor-swizzled
  __shared__ __align__(16) unsigned short sVT[128 * 64];  // [d][t] xor-swizzled
  __shared__ __align__(16) unsigned short sP[64 * 64];    // [q][t] swz(q)-swizzled
  const int h = blockIdx.y, b = blockIdx.z;
  const int tid = threadIdx.x, wave = tid >> 6, lane = tid & 63;
  const int quad = lane >> 4, cl = lane & 15;
  const int nq = T / 64;  // 32
  const int qt = nq - 1 - blockIdx.x;  // heavy q-tiles first

  // Q A-fragments in registers: rows wave*16+cl, k = kk*32 + quad*8 + jj
  // (Q pre-scaled by 1/sqrt(Dh)*log2e in the Q-projection GEMM epilogue)
  bf16x8 qf[4];
  {
    const unsigned short* Qg =
        Qm + (size_t)(b * T + qt * 64 + wave * 16 + cl) * ld + h * 128 + quad * 8;
#pragma unroll
    for (int kk = 0; kk < 4; ++kk)
      qf[kk] = *(const bf16x8*)(Qg + kk * 32);
  }

  float m_i[4], l_i[4];
  f32x4 acc_o[8] = {};
#pragma unroll
  for (int r = 0; r < 4; ++r) { m_i[r] = -1e30f; l_i[r] = 0.f; }

  for (int kt = 0; kt <= qt; ++kt) {
    const unsigned short* Kg = Km + (size_t)(b * T + kt * 64) * ld + h * 128;
    const unsigned short* Vg = Vt + (size_t)(h * 128) * ldv + (size_t)b * T + kt * 64;
    __syncthreads();  // previous tile's sK/sVT reads complete
#pragma unroll
    for (int r = 0; r < 4; ++r) {
      int c0 = r * 256 + wave * 64;
      int c = c0 + lane;
      int row = c >> 4, j = (c & 15) ^ (row & 7);
      async16(Kg + (size_t)row * ld + j * 8, (char*)sK + c0 * 16);
      int d = c >> 3, jv = (c & 7) ^ (d & 7);
      async16(Vg + (size_t)d * ldv + jv * 8, (char*)sVT + c0 * 16);
    }
    __syncthreads();  // staging complete

    // S = Q @ K^T : 16 q-rows (this wave) x 64 keys (exp2 domain, pre-scaled)
    f32x4 s[4] = {};
#pragma unroll
    for (int kk = 0; kk < 4; ++kk) {
#pragma unroll
      for (int j = 0; j < 4; ++j) {
        int t = j * 16 + cl;
        int jp = (kk * 4 + quad) ^ (t & 7);
        bf16x8 bk = *(const bf16x8*)((const char*)sK + (t * 16 + jp) * 16);
        s[j] = __builtin_amdgcn_mfma_f32_16x16x32_bf16(qf[kk], bk, s[j], 0, 0, 0);
      }
    }

    // causal mask + online softmax with deferred max
    const bool need_mask = (kt == qt);
#pragma unroll
    for (int r = 0; r < 4; ++r) {
      int q_l = wave * 16 + quad * 4 + r;  // local q row (tile row)
      float mx = -1e30f;
#pragma unroll
      for (int j = 0; j < 4; ++j) {
        float v = s[j][r];
        if (need_mask) {
          int t_l = j * 16 + cl;
          if (t_l > q_l) v = -1e30f;
          s[j][r] = v;
        }
        mx = fmaxf(mx, v);
      }
#pragma unroll
      for (int off = 1; off < 16; off <<= 1)
        mx = fmaxf(mx, __shfl_xor(mx, off));
      // rescale only when some covered row's max grew by > 6 (wave-uniform
      // branch). Skipped: P entries bounded by 2^6 = 64, fine in bf16, and
      // acc_o/l_i stay consistent (shared implicit scale exp2(m_true-m_i)).
      if (__any(mx > m_i[r] + 6.f)) {
        float m_new = fmaxf(m_i[r], mx);
        float alpha = exp2f(m_i[r] - m_new);
        m_i[r] = m_new;
        l_i[r] *= alpha;
#pragma unroll
        for (int jd = 0; jd < 8; ++jd)
          acc_o[jd][r] *= alpha;
      }
      float rs = 0.f;
#pragma unroll
      for (int j = 0; j < 4; ++j) {
        float p = exp2f(s[j][r] - m_i[r]);
        s[j][r] = p;
        rs += p;
      }
#pragma unroll
      for (int off = 1; off < 16; off <<= 1)
        rs += __shfl_xor(rs, off);
      l_i[r] += rs;
    }

    // write P swizzled into sP (wave-local rows -> no barrier needed)
    // swz(q) = (q&7) ^ (((q>>3)&1)<<1): all 4 quads hit disjoint bank sets
#pragma unroll
    for (int j = 0; j < 4; ++j)
#pragma unroll
      for (int r = 0; r < 4; ++r) {
        int q = wave * 16 + quad * 4 + r;
        int swz = (q & 7) ^ (((q >> 3) & 1) << 1);
        int t = j * 16 + cl;
        int jp = (t >> 3) ^ swz;
        sP[(q * 8 + jp) * 8 + (t & 7)] = f2b(s[j][r]);
      }

    // O += P @ V (A from own-wave sP rows, B from sVT; both b128)
#pragma unroll
    for (int kk2 = 0; kk2 < 2; ++kk2) {
      int q = wave * 16 + cl;
      int swz = (q & 7) ^ (((q >> 3) & 1) << 1);
      int jp = (kk2 * 4 + quad) ^ swz;
      bf16x8 ap = *(const bf16x8*)((const char*)sP + (q * 8 + jp) * 16);
#pragma unroll
      for (int jd = 0; jd < 8; ++jd) {
        int d = jd * 16 + cl;
        int jpv = (kk2 * 4 + quad) ^ (d & 7);
        bf16x8 bv = *(const bf16x8*)((const char*)sVT + (d * 8 + jpv) * 16);
        acc_o[jd] = __builtin_amdgcn_mfma_f32_16x16x32_bf16(ap, bv, acc_o[jd], 0, 0, 0);
      }
    }
  }

  // epilogue: normalize and store this q-tile
#pragma unroll
  for (int r = 0; r < 4; ++r) {
    float inv = 1.f / l_i[r];
    int row = b * T + qt * 64 + wave * 16 + quad * 4 + r;
#pragma unroll
    for (int jd = 0; jd < 8; ++jd)
      Om[(size_t)row * ld + h * 128 + jd * 16 + cl] = f2b(acc_o[jd][r] * inv);
  }
}

// ---------- launch ----------
extern "C" void kernel_launch(void* const* d_in, const int* in_sizes, int n_in,
                              void* d_out, int out_size, void* d_ws, size_t ws_size,
                              hipStream_t stream) {
  (void)in_sizes; (void)n_in; (void)out_size; (void)ws_size;
  const int B = 2, T = 2048, Dm = 2048, H = 16, Dh = 128, R = 512;
  const int M = B * T;  // 4096
  const float* x     = (const float*)d_in[0];
  const float* Wq    = (const float*)d_in[1];
  const float* Wdown = (const float*)d_in[2];
  const float* Wkup  = (const float*)d_in[3];
  const float* Wvup  = (const float*)d_in[4];
  const float* Wo    = (const float*)d_in[5];

  float* out  = (float*)d_out;                      // (B*T) x 2048 fp32
  float* cout = out + (size_t)M * Dm;               // (B*T) x 512  fp32

  unsigned short* ws  = (unsigned short*)d_ws;      // bf16 scratch
  unsigned short* WqT = ws;                         // 2048x2048
  unsigned short* WoT = WqT + (size_t)Dm * Dm;      // 2048x2048
  unsigned short* WdT = WoT + (size_t)Dm * Dm;      // 512x2048
  unsigned short* WkT = WdT + (size_t)R * Dm;       // 2048x512
  unsigned short* WvT = WkT + (size_t)Dm * R;       // 2048x512
  unsigned short* xb  = WvT + (size_t)Dm * R;       // 4096x2048 (reused as AO)
  unsigned short* cb  = xb + (size_t)M * Dm;        // 4096x512
  unsigned short* Qb  = cb + (size_t)M * R;         // 4096x2048
  unsigned short* Kb  = Qb + (size_t)M * Dm;
  unsigned short* Vb  = Kb + (size_t)M * Dm;
  unsigned short* Vtb = Vb + (size_t)M * Dm;        // 2048x4096 (V^T, d-major)
  unsigned short* AO  = xb;                         // alias: xb dead after Q-proj

  // softmax scale folded into Q: 1/sqrt(128) * log2(e)
  const float qscale = 0.08838834764831845f * 1.4426950408889634f;

  // input casts / weight transposes -> bf16 BT form
  cast_f32_bf16<<<(M * Dm) / 1024, 256, 0, stream>>>(x, xb, M * Dm);
  transpose_cast<<<dim3(32, 32), 256, 0, stream>>>(Wq, WqT, Dm, Dm);
  transpose_cast<<<dim3(32, 32), 256, 0, stream>>>(Wo, WoT, Dm, Dm);
  transpose_cast<<<dim3(8, 32), 256, 0, stream>>>(Wdown, WdT, Dm, R);
  transpose_cast<<<dim3(32, 8), 256, 0, stream>>>(Wkup, WkT, R, Dm);
  transpose_cast<<<dim3(32, 8), 256, 0, stream>>>(Wvup, WvT, R, Dm);

  // projections
  gemm_bt<<<dim3(R / 128, M / 128), 256, 0, stream>>>(xb, WdT, cb, cout, M, R, Dm, 1.f);        // c
  gemm_bt<<<dim3(Dm / 128, M / 128), 256, 0, stream>>>(xb, WqT, Qb, nullptr, M, Dm, Dm, qscale); // Q (pre-scaled)
  gemm_bt<<<dim3(Dm / 128, M / 128), 256, 0, stream>>>(cb, WkT, Kb, nullptr, M, Dm, R, 1.f);     // K
  gemm_bt<<<dim3(Dm / 128, M / 128), 256, 0, stream>>>(cb, WvT, Vb, nullptr, M, Dm, R, 1.f);     // V

  // V -> V^T (d-major) for conflict-free PV B-fragments
  transpose_bf16<<<dim3(Dm / 64, M / 64), 256, 0, stream>>>(Vb, Vtb, M, Dm);

  // causal attention: one 64-row q-tile per block, heavy-first
  mla_attn<<<dim3(T / 64, H, B), 256, 0, stream>>>(Qb, Kb, Vtb, AO, T);

  // output projection (fp32 out)
  gemm_bt<<<dim3(Dm / 128, M / 128), 256, 0, stream>>>(AO, WoT, nullptr, out, M, Dm, Dm, 1.f);
  (void)Dh; (void)H;
}

// Round 3
// 410.643 us; speedup vs baseline: 1.2549x; 1.2549x over previous
//
#include <hip/hip_runtime.h>

// ---------- common helpers ----------
typedef short bf16x8 __attribute__((ext_vector_type(8)));
typedef float f32x4 __attribute__((ext_vector_type(4)));

__device__ __forceinline__ void async16(const void* g, const void* l) {
  __builtin_amdgcn_global_load_lds(
      (const __attribute__((address_space(1))) unsigned int*)g,
      (__attribute__((address_space(3))) unsigned int*)(void*)(uintptr_t)l,
      16, 0, 0);
}

__device__ __forceinline__ unsigned short f2b(float f) {
  unsigned int u = __float_as_uint(f);
  u += 0x7fffu + ((u >> 16) & 1u);   // round-to-nearest-even
  return (unsigned short)(u >> 16);
}

// ---------- cast fp32 -> bf16, n % 1024 == 0 ----------
__global__ __launch_bounds__(256) void cast_f32_bf16(
    const float* __restrict__ in, unsigned short* __restrict__ out, int n) {
  int i = (blockIdx.x * 256 + threadIdx.x) * 4;
  if (i < n) {
    float4 v = *(const float4*)(in + i);
    ushort4 o;
    o.x = f2b(v.x); o.y = f2b(v.y); o.z = f2b(v.z); o.w = f2b(v.w);
    *(ushort4*)(out + i) = o;
  }
}

// ---------- transpose+cast: out_bf16[N][K] = in_f32[K][N], K,N multiples of 64 ----------
__global__ __launch_bounds__(256) void transpose_cast(
    const float* __restrict__ in, unsigned short* __restrict__ out,
    int K, int N) {
  __shared__ __align__(16) unsigned short tile[64][65];
  const int k0 = blockIdx.y * 64, n0 = blockIdx.x * 64;
  const int tid = threadIdx.x;
  const int r = tid >> 4, c4 = tid & 15;
#pragma unroll
  for (int p = 0; p < 4; ++p) {
    int row = p * 16 + r;
    float4 v = *(const float4*)(in + (size_t)(k0 + row) * N + n0 + c4 * 4);
    tile[c4 * 4 + 0][row] = f2b(v.x);
    tile[c4 * 4 + 1][row] = f2b(v.y);
    tile[c4 * 4 + 2][row] = f2b(v.z);
    tile[c4 * 4 + 3][row] = f2b(v.w);
  }
  __syncthreads();
#pragma unroll
  for (int p = 0; p < 4; ++p) {
    int nr = p * 16 + r;
    ushort4 o;
    o.x = tile[nr][c4 * 4 + 0];
    o.y = tile[nr][c4 * 4 + 1];
    o.z = tile[nr][c4 * 4 + 2];
    o.w = tile[nr][c4 * 4 + 3];
    *(ushort4*)(out + (size_t)(n0 + nr) * K + k0 + c4 * 4) = o;
  }
}

// ---------- transpose bf16: out[N][K] = in[K][N], K,N multiples of 64 ----------
__global__ __launch_bounds__(256) void transpose_bf16(
    const unsigned short* __restrict__ in, unsigned short* __restrict__ out,
    int K, int N) {
  __shared__ __align__(16) unsigned short tile[64][65];
  const int k0 = blockIdx.y * 64, n0 = blockIdx.x * 64;
  const int tid = threadIdx.x;
  const int r = tid >> 4, c4 = tid & 15;
#pragma unroll
  for (int p = 0; p < 4; ++p) {
    int row = p * 16 + r;
    ushort4 v = *(const ushort4*)(in + (size_t)(k0 + row) * N + n0 + c4 * 4);
    tile[c4 * 4 + 0][row] = v.x;
    tile[c4 * 4 + 1][row] = v.y;
    tile[c4 * 4 + 2][row] = v.z;
    tile[c4 * 4 + 3][row] = v.w;
  }
  __syncthreads();
#pragma unroll
  for (int p = 0; p < 4; ++p) {
    int nr = p * 16 + r;
    ushort4 o;
    o.x = tile[nr][c4 * 4 + 0];
    o.y = tile[nr][c4 * 4 + 1];
    o.z = tile[nr][c4 * 4 + 2];
    o.w = tile[nr][c4 * 4 + 3];
    *(ushort4*)(out + (size_t)(n0 + nr) * K + k0 + c4 * 4) = o;
  }
}

// ---------- GEMM: C[M,N] = A[M,K] @ BT[N,K]^T (bf16 in, fp32 accum) ----------
// M%128==0, N%128==0, K%64==0. m97-style: 128x128 tile, BK=64, 4 waves 2x2.
// cscale multiplies the bf16 (Cb) output only (used to pre-scale Q by
// 1/sqrt(Dh)*log2e so attention's softmax has no per-score multiply).
__global__ __launch_bounds__(256) void gemm_bt(
    const unsigned short* __restrict__ A, const unsigned short* __restrict__ BT,
    unsigned short* __restrict__ Cb, float* __restrict__ Cf, int M, int N, int K,
    float cscale) {
  __shared__ __align__(16) unsigned short sA[128 * 64];
  __shared__ __align__(16) unsigned short sB[128 * 64];
  const int tid = threadIdx.x;
  const int wave = tid >> 6, lane = tid & 63;
  const int quad = lane >> 4, cl = lane & 15;
  const int m0 = blockIdx.y * 128, n0 = blockIdx.x * 128;
  const int wm = (wave >> 1) * 64, wn = (wave & 1) * 64;
  (void)M;

  f32x4 acc[4][4] = {};

  const unsigned short* gA = A + (size_t)(m0 + wave * 32 + (lane >> 3)) * K + (lane & 7) * 8;
  const unsigned short* gB = BT + (size_t)(n0 + wave * 32 + (lane >> 3)) * K + (lane & 7) * 8;
  char* lA = (char*)sA + (wave * 32) * 128;
  char* lB = (char*)sB + (wave * 32) * 128;

  for (int kt = 0; kt < K; kt += 64) {
#pragma unroll
    for (int r = 0; r < 4; ++r) {
      async16(gA + (size_t)r * 8 * K + kt, lA + r * 8 * 128);
      async16(gB + (size_t)r * 8 * K + kt, lB + r * 8 * 128);
    }
    __syncthreads();
#pragma unroll
    for (int kk = 0; kk < 64; kk += 32) {
      bf16x8 af[4], bfr[4];
#pragma unroll
      for (int i = 0; i < 4; ++i)
        af[i] = *(const bf16x8*)((const char*)sA + (wm + i * 16 + cl) * 128 + kk * 2 + quad * 16);
#pragma unroll
      for (int j = 0; j < 4; ++j)
        bfr[j] = *(const bf16x8*)((const char*)sB + (wn + j * 16 + cl) * 128 + kk * 2 + quad * 16);
#pragma unroll
      for (int i = 0; i < 4; ++i)
#pragma unroll
        for (int j = 0; j < 4; ++j)
          acc[i][j] = __builtin_amdgcn_mfma_f32_16x16x32_bf16(af[i], bfr[j], acc[i][j], 0, 0, 0);
    }
    __syncthreads();
  }
#pragma unroll
  for (int i = 0; i < 4; ++i)
#pragma unroll
    for (int j = 0; j < 4; ++j)
#pragma unroll
      for (int r = 0; r < 4; ++r) {
        int row = m0 + wm + i * 16 + quad * 4 + r;
        int col = n0 + wn + j * 16 + cl;
        float v = acc[i][j][r];
        if (Cb) Cb[(size_t)row * N + col] = f2b(v * cscale);
        if (Cf) Cf[(size_t)row * N + col] = v;
      }
}

// ---------- flash-style causal attention, v6 ----------
// Back to v3's proven shell: grid (T/128, H, B) = (16,16,2) = 512 blocks,
// 256 threads, balanced q-tile pair {bx, 31-bx} -> every block exactly 33
// k-tiles, 2 blocks/CU. No __launch_bounds__ min-waves (v5's (256,4) caused
// VGPR spill: 64 VGPR + 65MB scratch writes).
// v6 change: software-pipelined staging inside the 2-blocks/CU LDS budget.
// Only K is double-buffered (LDS 56KB = 2x16K sK + 16K sVT + 8K sP; 2x56 <=
// 160 so residency is preserved). Per tile:
//   top:  issue K[kt+1]->sK[nxt]  (dbuf overlaps QK^T reads of sK[cur])
//         issue V[kt]  ->sVT      (prev PV reads done at B2)
//         QK^T + softmax + P-write   <- ~full phase covers both loads
//   B1:   barrier (drain hidden; also ends sK[cur] reads)
//         PV (sVT, sP)
//   B2:   barrier (pure sync: protects sVT for next tile's V issue)
// v3 drained the staging cold at B-stage with zero covering compute -> ~40%
// stall. Also: l-reduce deferred to epilogue (per-lane partials, alpha is
// wave-uniform); defer-max check uses lane-local max, full 4-shfl max reduce
// only inside the rare rescale branch; softmax scale pre-folded into Q.
__global__ __launch_bounds__(256) void mla_attn(
    const unsigned short* __restrict__ Qm, const unsigned short* __restrict__ Km,
    const unsigned short* __restrict__ Vt, unsigned short* __restrict__ Om, int T) {
  const int ld = 2048;
  const int ldv = 4096;  // B*T
  __shared__ __align__(16) unsigned short sK[2][64 * 128];  // [t][d] xor-swizzled
  __shared__ __align__(16) unsigned short sVT[128 * 64];    // [d][t] xor-swizzled
  __shared__ __align__(16) unsigned short sP[64 * 64];      // [q][t] swz(q)-swizzled
  const int h = blockIdx.y, b = blockIdx.z;
  const int tid = threadIdx.x, wave = tid >> 6, lane = tid & 63;
  const int quad = lane >> 4, cl = lane & 15;
  const int nq = T / 64;  // 32

  for (int phase = 0; phase < 2; ++phase) {
    const int qt = phase ? (nq - 1 - blockIdx.x) : blockIdx.x;

    // Q A-fragments in registers: rows wave*16+cl, k = kk*32 + quad*8 + jj
    // (Q pre-scaled by 1/sqrt(Dh)*log2e in the Q-projection GEMM epilogue)
    bf16x8 qf[4];
    {
      const unsigned short* Qg =
          Qm + (size_t)(b * T + qt * 64 + wave * 16 + cl) * ld + h * 128 + quad * 8;
#pragma unroll
      for (int kk = 0; kk < 4; ++kk)
        qf[kk] = *(const bf16x8*)(Qg + kk * 32);
    }

    float m_i[4], l_part[4];
    f32x4 acc_o[8] = {};
#pragma unroll
    for (int r = 0; r < 4; ++r) { m_i[r] = -1e30f; l_part[r] = 0.f; }

    const unsigned short* Kg0 = Km + (size_t)(b * T) * ld + h * 128;
    const unsigned short* Vg0 = Vt + (size_t)(h * 128) * ldv + (size_t)b * T;

    // prologue: stage K[0] into buffer 0 (prior-phase LDS reads all ended
    // before the prior phase's final B2/B1 barriers).
#pragma unroll
    for (int r = 0; r < 4; ++r) {
      int c0 = r * 256 + wave * 64;
      int c = c0 + lane;
      int row = c >> 4, j = (c & 15) ^ (row & 7);
      async16(Kg0 + (size_t)row * ld + j * 8, (char*)sK[0] + c0 * 16);
    }
    __syncthreads();  // drain K[0] (and phase's Q register loads)

    for (int kt = 0; kt <= qt; ++kt) {
      const int cur = kt & 1;
      const char* cK = (const char*)sK[cur];

      // issue next K tile into the other buffer (overlaps QK^T on sK[cur])
      if (kt < qt) {
        const unsigned short* Kg = Kg0 + (size_t)(kt + 1) * 64 * ld;
        char* dK = (char*)sK[cur ^ 1];
#pragma unroll
        for (int r = 0; r < 4; ++r) {
          int c0 = r * 256 + wave * 64;
          int c = c0 + lane;
          int row = c >> 4, j = (c & 15) ^ (row & 7);
          async16(Kg + (size_t)row * ld + j * 8, dK + c0 * 16);
        }
      }
      // issue this tile's V (prev PV reads of sVT completed at B2)
      {
        const unsigned short* Vg = Vg0 + kt * 64;
#pragma unroll
        for (int r = 0; r < 4; ++r) {
          int c0 = r * 256 + wave * 64;
          int c = c0 + lane;
          int d = c >> 3, jv = (c & 7) ^ (d & 7);
          async16(Vg + (size_t)d * ldv + jv * 8, (char*)sVT + c0 * 16);
        }
      }

      // S = Q @ K^T : 16 q-rows (this wave) x 64 keys (exp2 domain, pre-scaled)
      f32x4 s[4] = {};
#pragma unroll
      for (int kk = 0; kk < 4; ++kk) {
#pragma unroll
        for (int j = 0; j < 4; ++j) {
          int t = j * 16 + cl;
          int jp = (kk * 4 + quad) ^ (t & 7);
          bf16x8 bk = *(const bf16x8*)(cK + (t * 16 + jp) * 16);
          s[j] = __builtin_amdgcn_mfma_f32_16x16x32_bf16(qf[kk], bk, s[j], 0, 0, 0);
        }
      }

      // causal mask + online softmax (deferred max, lane-local fast path)
      const bool need_mask = (kt == qt);
#pragma unroll
      for (int r = 0; r < 4; ++r) {
        int q_l = wave * 16 + quad * 4 + r;  // local q row (tile row)
        float mxl = -1e30f;
#pragma unroll
        for (int j = 0; j < 4; ++j) {
          float v = s[j][r];
          if (need_mask) {
            int t_l = j * 16 + cl;
            if (t_l > q_l) v = -1e30f;
            s[j][r] = v;
          }
          mxl = fmaxf(mxl, v);
        }
        // fast check on lane-local max; shfl reduce only in the rare branch.
        // Skipped-rescale keeps P bounded by 2^6 = 64 (bf16-safe); l_part and
        // acc_o stay consistent (shared implicit scale exp2(m_true - m_i)).
        if (__any(mxl > m_i[r] + 6.f)) {
          float mx = mxl;
#pragma unroll
          for (int off = 1; off < 16; off <<= 1)
            mx = fmaxf(mx, __shfl_xor(mx, off));
          float m_new = fmaxf(m_i[r], mx);
          float alpha = exp2f(m_i[r] - m_new);
          m_i[r] = m_new;
          l_part[r] *= alpha;
#pragma unroll
          for (int jd = 0; jd < 8; ++jd)
            acc_o[jd][r] *= alpha;
        }
        float rs = 0.f;
#pragma unroll
        for (int j = 0; j < 4; ++j) {
          float p = exp2f(s[j][r] - m_i[r]);
          s[j][r] = p;
          rs += p;
        }
        l_part[r] += rs;  // per-lane partial; cross-lane reduce in epilogue
      }

      // write P swizzled into sP (wave-local rows -> no barrier needed)
      // swz(q) = (q&7) ^ (((q>>3)&1)<<1): all 4 quads hit disjoint bank sets
#pragma unroll
      for (int j = 0; j < 4; ++j)
#pragma unroll
        for (int r = 0; r < 4; ++r) {
          int q = wave * 16 + quad * 4 + r;
          int swz = (q & 7) ^ (((q >> 3) & 1) << 1);
          int t = j * 16 + cl;
          int jp = (t >> 3) ^ swz;
          sP[(q * 8 + jp) * 8 + (t & 7)] = f2b(s[j][r]);
        }

      __syncthreads();  // B1: drains K[kt+1]+V[kt] (covered); sK[cur] reads done

      // O += P @ V (A from own-wave sP rows, B from sVT; both b128)
#pragma unroll
      for (int kk2 = 0; kk2 < 2; ++kk2) {
        int q = wave * 16 + cl;
        int swz = (q & 7) ^ (((q >> 3) & 1) << 1);
        int jp = (kk2 * 4 + quad) ^ swz;
        bf16x8 ap = *(const bf16x8*)((const char*)sP + (q * 8 + jp) * 16);
#pragma unroll
        for (int jd = 0; jd < 8; ++jd) {
          int d = jd * 16 + cl;
          int jpv = (kk2 * 4 + quad) ^ (d & 7);
          bf16x8 bv = *(const bf16x8*)((const char*)sVT + (d * 8 + jpv) * 16);
          acc_o[jd] = __builtin_amdgcn_mfma_f32_16x16x32_bf16(ap, bv, acc_o[jd], 0, 0, 0);
        }
      }

      __syncthreads();  // B2: pure sync — sVT reads done before next V issue
    }

    // epilogue: reduce l partials across the 16 row lanes, normalize, store
#pragma unroll
    for (int r = 0; r < 4; ++r) {
      float l = l_part[r];
#pragma unroll
      for (int off = 1; off < 16; off <<= 1)
        l += __shfl_xor(l, off);
      float inv = 1.f / l;
      int row = b * T + qt * 64 + wave * 16 + quad * 4 + r;
#pragma unroll
      for (int jd = 0; jd < 8; ++jd)
        Om[(size_t)row * ld + h * 128 + jd * 16 + cl] = f2b(acc_o[jd][r] * inv);
    }
  }
}

// ---------- launch ----------
extern "C" void kernel_launch(void* const* d_in, const int* in_sizes, int n_in,
                              void* d_out, int out_size, void* d_ws, size_t ws_size,
                              hipStream_t stream) {
  (void)in_sizes; (void)n_in; (void)out_size; (void)ws_size;
  const int B = 2, T = 2048, Dm = 2048, H = 16, Dh = 128, R = 512;
  const int M = B * T;  // 4096
  const float* x     = (const float*)d_in[0];
  const float* Wq    = (const float*)d_in[1];
  const float* Wdown = (const float*)d_in[2];
  const float* Wkup  = (const float*)d_in[3];
  const float* Wvup  = (const float*)d_in[4];
  const float* Wo    = (const float*)d_in[5];

  float* out  = (float*)d_out;                      // (B*T) x 2048 fp32
  float* cout = out + (size_t)M * Dm;               // (B*T) x 512  fp32

  unsigned short* ws  = (unsigned short*)d_ws;      // bf16 scratch
  unsigned short* WqT = ws;                         // 2048x2048
  unsigned short* WoT = WqT + (size_t)Dm * Dm;      // 2048x2048
  unsigned short* WdT = WoT + (size_t)Dm * Dm;      // 512x2048
  unsigned short* WkT = WdT + (size_t)R * Dm;       // 2048x512
  unsigned short* WvT = WkT + (size_t)Dm * R;       // 2048x512
  unsigned short* xb  = WvT + (size_t)Dm * R;       // 4096x2048 (reused as AO)
  unsigned short* cb  = xb + (size_t)M * Dm;        // 4096x512
  unsigned short* Qb  = cb + (size_t)M * R;         // 4096x2048
  unsigned short* Kb  = Qb + (size_t)M * Dm;
  unsigned short* Vb  = Kb + (size_t)M * Dm;
  unsigned short* Vtb = Vb + (size_t)M * Dm;        // 2048x4096 (V^T, d-major)
  unsigned short* AO  = xb;                         // alias: xb dead after Q-proj

  // softmax scale folded into Q: 1/sqrt(128) * log2(e)
  const float qscale = 0.08838834764831845f * 1.4426950408889634f;

  // input casts / weight transposes -> bf16 BT form
  cast_f32_bf16<<<(M * Dm) / 1024, 256, 0, stream>>>(x, xb, M * Dm);
  transpose_cast<<<dim3(32, 32), 256, 0, stream>>>(Wq, WqT, Dm, Dm);
  transpose_cast<<<dim3(32, 32), 256, 0, stream>>>(Wo, WoT, Dm, Dm);
  transpose_cast<<<dim3(8, 32), 256, 0, stream>>>(Wdown, WdT, Dm, R);
  transpose_cast<<<dim3(32, 8), 256, 0, stream>>>(Wkup, WkT, R, Dm);
  transpose_cast<<<dim3(32, 8), 256, 0, stream>>>(Wvup, WvT, R, Dm);

  // projections
  gemm_bt<<<dim3(R / 128, M / 128), 256, 0, stream>>>(xb, WdT, cb, cout, M, R, Dm, 1.f);        // c
  gemm_bt<<<dim3(Dm / 128, M / 128), 256, 0, stream>>>(xb, WqT, Qb, nullptr, M, Dm, Dm, qscale); // Q (pre-scaled)
  gemm_bt<<<dim3(Dm / 128, M / 128), 256, 0, stream>>>(cb, WkT, Kb, nullptr, M, Dm, R, 1.f);     // K
  gemm_bt<<<dim3(Dm / 128, M / 128), 256, 0, stream>>>(cb, WvT, Vb, nullptr, M, Dm, R, 1.f);     // V

  // V -> V^T (d-major) for conflict-free PV B-fragments
  transpose_bf16<<<dim3(Dm / 64, M / 64), 256, 0, stream>>>(Vb, Vtb, M, Dm);

  // causal attention: balanced pair {bx, 31-bx} per block
  mla_attn<<<dim3(T / 128, H, B), 256, 0, stream>>>(Qb, Kb, Vtb, AO, T);

  // output projection (fp32 out)
  gemm_bt<<<dim3(Dm / 128, M / 128), 256, 0, stream>>>(AO, WoT, nullptr, out, M, Dm, Dm, 1.f);
  (void)Dh; (void)H;
}

// Round 4
// 398.732 us; speedup vs baseline: 1.2924x; 1.0299x over previous
//
#include <hip/hip_runtime.h>

// ---------- common helpers ----------
typedef short bf16x8 __attribute__((ext_vector_type(8)));
typedef float f32x4 __attribute__((ext_vector_type(4)));

__device__ __forceinline__ void async16(const void* g, const void* l) {
  __builtin_amdgcn_global_load_lds(
      (const __attribute__((address_space(1))) unsigned int*)g,
      (__attribute__((address_space(3))) unsigned int*)(void*)(uintptr_t)l,
      16, 0, 0);
}

__device__ __forceinline__ unsigned short f2b(float f) {
  unsigned int u = __float_as_uint(f);
  u += 0x7fffu + ((u >> 16) & 1u);   // round-to-nearest-even
  return (unsigned short)(u >> 16);
}

// ---------- cast fp32 -> bf16, n % 1024 == 0 ----------
__global__ __launch_bounds__(256) void cast_f32_bf16(
    const float* __restrict__ in, unsigned short* __restrict__ out, int n) {
  int i = (blockIdx.x * 256 + threadIdx.x) * 4;
  if (i < n) {
    float4 v = *(const float4*)(in + i);
    ushort4 o;
    o.x = f2b(v.x); o.y = f2b(v.y); o.z = f2b(v.z); o.w = f2b(v.w);
    *(ushort4*)(out + i) = o;
  }
}

// ---------- transpose+cast: out_bf16[N][K] = in_f32[K][N], K,N multiples of 64 ----------
__global__ __launch_bounds__(256) void transpose_cast(
    const float* __restrict__ in, unsigned short* __restrict__ out,
    int K, int N) {
  __shared__ __align__(16) unsigned short tile[64][65];
  const int k0 = blockIdx.y * 64, n0 = blockIdx.x * 64;
  const int tid = threadIdx.x;
  const int r = tid >> 4, c4 = tid & 15;
#pragma unroll
  for (int p = 0; p < 4; ++p) {
    int row = p * 16 + r;
    float4 v = *(const float4*)(in + (size_t)(k0 + row) * N + n0 + c4 * 4);
    tile[c4 * 4 + 0][row] = f2b(v.x);
    tile[c4 * 4 + 1][row] = f2b(v.y);
    tile[c4 * 4 + 2][row] = f2b(v.z);
    tile[c4 * 4 + 3][row] = f2b(v.w);
  }
  __syncthreads();
#pragma unroll
  for (int p = 0; p < 4; ++p) {
    int nr = p * 16 + r;
    ushort4 o;
    o.x = tile[nr][c4 * 4 + 0];
    o.y = tile[nr][c4 * 4 + 1];
    o.z = tile[nr][c4 * 4 + 2];
    o.w = tile[nr][c4 * 4 + 3];
    *(ushort4*)(out + (size_t)(n0 + nr) * K + k0 + c4 * 4) = o;
  }
}

// ---------- GEMM: C[M,N] = A[M,K] @ BT[N,K]^T (bf16 in, fp32 accum) ----------
// M%128==0, N%128==0, K%64==0. m97-style: 128x128 tile, BK=64, 4 waves 2x2.
__global__ __launch_bounds__(256) void gemm_bt(
    const unsigned short* __restrict__ A, const unsigned short* __restrict__ BT,
    unsigned short* __restrict__ Cb, float* __restrict__ Cf, int M, int N, int K,
    float cscale) {
  __shared__ __align__(16) unsigned short sA[128 * 64];
  __shared__ __align__(16) unsigned short sB[128 * 64];
  const int tid = threadIdx.x;
  const int wave = tid >> 6, lane = tid & 63;
  const int quad = lane >> 4, cl = lane & 15;
  const int m0 = blockIdx.y * 128, n0 = blockIdx.x * 128;
  const int wm = (wave >> 1) * 64, wn = (wave & 1) * 64;
  (void)M;

  f32x4 acc[4][4] = {};

  const unsigned short* gA = A + (size_t)(m0 + wave * 32 + (lane >> 3)) * K + (lane & 7) * 8;
  const unsigned short* gB = BT + (size_t)(n0 + wave * 32 + (lane >> 3)) * K + (lane & 7) * 8;
  char* lA = (char*)sA + (wave * 32) * 128;
  char* lB = (char*)sB + (wave * 32) * 128;

  for (int kt = 0; kt < K; kt += 64) {
#pragma unroll
    for (int r = 0; r < 4; ++r) {
      async16(gA + (size_t)r * 8 * K + kt, lA + r * 8 * 128);
      async16(gB + (size_t)r * 8 * K + kt, lB + r * 8 * 128);
    }
    __syncthreads();
#pragma unroll
    for (int kk = 0; kk < 64; kk += 32) {
      bf16x8 af[4], bfr[4];
#pragma unroll
      for (int i = 0; i < 4; ++i)
        af[i] = *(const bf16x8*)((const char*)sA + (wm + i * 16 + cl) * 128 + kk * 2 + quad * 16);
#pragma unroll
      for (int j = 0; j < 4; ++j)
        bfr[j] = *(const bf16x8*)((const char*)sB + (wn + j * 16 + cl) * 128 + kk * 2 + quad * 16);
#pragma unroll
      for (int i = 0; i < 4; ++i)
#pragma unroll
        for (int j = 0; j < 4; ++j)
          acc[i][j] = __builtin_amdgcn_mfma_f32_16x16x32_bf16(af[i], bfr[j], acc[i][j], 0, 0, 0);
    }
    __syncthreads();
  }
#pragma unroll
  for (int i = 0; i < 4; ++i)
#pragma unroll
    for (int j = 0; j < 4; ++j)
#pragma unroll
      for (int r = 0; r < 4; ++r) {
        int row = m0 + wm + i * 16 + quad * 4 + r;
        int col = n0 + wn + j * 16 + cl;
        float v = acc[i][j][r];
        if (Cb) Cb[(size_t)row * N + col] = f2b(v * cscale);
        if (Cf) Cf[(size_t)row * N + col] = v;
      }
}

// ---------- fused Q+c projection GEMM ----------
// C[M,2560] = xb[M,2048] @ [WqT;WdT]^T. Stacked BT: rows 0..2047 = WqT
// (Wq columns), rows 2048..2559 = WdT (Wdown columns). Epilogue splits:
// cols <2048 -> Qb (bf16, *qscale, ld 2048); cols >=2048 -> cb (bf16, ld 512)
// + cout (fp32, ld 512). Removes the separate 128-block c-GEMM whose grid
// filled only 1/4 of the 512 two-block/CU slots (~3/4 GPU idle for a full
// 32-K-iter block time).
__global__ __launch_bounds__(256) void gemm_qc(
    const unsigned short* __restrict__ A, const unsigned short* __restrict__ BT,
    unsigned short* __restrict__ Qb, unsigned short* __restrict__ cb,
    float* __restrict__ cout, int K, float qscale) {
  __shared__ __align__(16) unsigned short sA[128 * 64];
  __shared__ __align__(16) unsigned short sB[128 * 64];
  const int tid = threadIdx.x;
  const int wave = tid >> 6, lane = tid & 63;
  const int quad = lane >> 4, cl = lane & 15;
  const int m0 = blockIdx.y * 128, n0 = blockIdx.x * 128;
  const int wm = (wave >> 1) * 64, wn = (wave & 1) * 64;

  f32x4 acc[4][4] = {};

  const unsigned short* gA = A + (size_t)(m0 + wave * 32 + (lane >> 3)) * K + (lane & 7) * 8;
  const unsigned short* gB = BT + (size_t)(n0 + wave * 32 + (lane >> 3)) * K + (lane & 7) * 8;
  char* lA = (char*)sA + (wave * 32) * 128;
  char* lB = (char*)sB + (wave * 32) * 128;

  for (int kt = 0; kt < K; kt += 64) {
#pragma unroll
    for (int r = 0; r < 4; ++r) {
      async16(gA + (size_t)r * 8 * K + kt, lA + r * 8 * 128);
      async16(gB + (size_t)r * 8 * K + kt, lB + r * 8 * 128);
    }
    __syncthreads();
#pragma unroll
    for (int kk = 0; kk < 64; kk += 32) {
      bf16x8 af[4], bfr[4];
#pragma unroll
      for (int i = 0; i < 4; ++i)
        af[i] = *(const bf16x8*)((const char*)sA + (wm + i * 16 + cl) * 128 + kk * 2 + quad * 16);
#pragma unroll
      for (int j = 0; j < 4; ++j)
        bfr[j] = *(const bf16x8*)((const char*)sB + (wn + j * 16 + cl) * 128 + kk * 2 + quad * 16);
#pragma unroll
      for (int i = 0; i < 4; ++i)
#pragma unroll
        for (int j = 0; j < 4; ++j)
          acc[i][j] = __builtin_amdgcn_mfma_f32_16x16x32_bf16(af[i], bfr[j], acc[i][j], 0, 0, 0);
    }
    __syncthreads();
  }
  const bool qreg = (n0 < 2048);  // block-uniform (2048 % 128 == 0)
#pragma unroll
  for (int i = 0; i < 4; ++i)
#pragma unroll
    for (int j = 0; j < 4; ++j)
#pragma unroll
      for (int r = 0; r < 4; ++r) {
        int row = m0 + wm + i * 16 + quad * 4 + r;
        int col = n0 + wn + j * 16 + cl;
        float v = acc[i][j][r];
        if (qreg) {
          Qb[(size_t)row * 2048 + col] = f2b(v * qscale);
        } else {
          int c2 = col - 2048;
          cb[(size_t)row * 512 + c2] = f2b(v);
          cout[(size_t)row * 512 + c2] = v;
        }
      }
}

// ---------- flash-style causal attention, v7 ----------
// v6 shell (95.4 us verified): grid (16,16,2), 256 thr, balanced pair
// {bx, 31-bx} (33 k-tiles/block), K double-buffered (LDS 56KB, 2 blocks/CU),
// V staged under QK^T+softmax cover, B1 drains hidden, B2 pure sync.
// v7: + s_setprio(1) around both MFMA clusters (T5); V^T now produced
// directly by a GEMM (no transpose kernel) -- attn unchanged otherwise.
__global__ __launch_bounds__(256) void mla_attn(
    const unsigned short* __restrict__ Qm, const unsigned short* __restrict__ Km,
    const unsigned short* __restrict__ Vt, unsigned short* __restrict__ Om, int T) {
  const int ld = 2048;
  const int ldv = 4096;  // B*T
  __shared__ __align__(16) unsigned short sK[2][64 * 128];  // [t][d] xor-swizzled
  __shared__ __align__(16) unsigned short sVT[128 * 64];    // [d][t] xor-swizzled
  __shared__ __align__(16) unsigned short sP[64 * 64];      // [q][t] swz(q)-swizzled
  const int h = blockIdx.y, b = blockIdx.z;
  const int tid = threadIdx.x, wave = tid >> 6, lane = tid & 63;
  const int quad = lane >> 4, cl = lane & 15;
  const int nq = T / 64;  // 32

  for (int phase = 0; phase < 2; ++phase) {
    const int qt = phase ? (nq - 1 - blockIdx.x) : blockIdx.x;

    // Q A-fragments in registers (pre-scaled by 1/sqrt(Dh)*log2e in Q-GEMM)
    bf16x8 qf[4];
    {
      const unsigned short* Qg =
          Qm + (size_t)(b * T + qt * 64 + wave * 16 + cl) * ld + h * 128 + quad * 8;
#pragma unroll
      for (int kk = 0; kk < 4; ++kk)
        qf[kk] = *(const bf16x8*)(Qg + kk * 32);
    }

    float m_i[4], l_part[4];
    f32x4 acc_o[8] = {};
#pragma unroll
    for (int r = 0; r < 4; ++r) { m_i[r] = -1e30f; l_part[r] = 0.f; }

    const unsigned short* Kg0 = Km + (size_t)(b * T) * ld + h * 128;
    const unsigned short* Vg0 = Vt + (size_t)(h * 128) * ldv + (size_t)b * T;

    // prologue: stage K[0] into buffer 0
#pragma unroll
    for (int r = 0; r < 4; ++r) {
      int c0 = r * 256 + wave * 64;
      int c = c0 + lane;
      int row = c >> 4, j = (c & 15) ^ (row & 7);
      async16(Kg0 + (size_t)row * ld + j * 8, (char*)sK[0] + c0 * 16);
    }
    __syncthreads();  // drain K[0] (and phase's Q register loads)

    for (int kt = 0; kt <= qt; ++kt) {
      const int cur = kt & 1;
      const char* cK = (const char*)sK[cur];

      // issue next K tile into the other buffer (overlaps QK^T on sK[cur])
      if (kt < qt) {
        const unsigned short* Kg = Kg0 + (size_t)(kt + 1) * 64 * ld;
        char* dK = (char*)sK[cur ^ 1];
#pragma unroll
        for (int r = 0; r < 4; ++r) {
          int c0 = r * 256 + wave * 64;
          int c = c0 + lane;
          int row = c >> 4, j = (c & 15) ^ (row & 7);
          async16(Kg + (size_t)row * ld + j * 8, dK + c0 * 16);
        }
      }
      // issue this tile's V (prev PV reads of sVT completed at B2)
      {
        const unsigned short* Vg = Vg0 + kt * 64;
#pragma unroll
        for (int r = 0; r < 4; ++r) {
          int c0 = r * 256 + wave * 64;
          int c = c0 + lane;
          int d = c >> 3, jv = (c & 7) ^ (d & 7);
          async16(Vg + (size_t)d * ldv + jv * 8, (char*)sVT + c0 * 16);
        }
      }

      // S = Q @ K^T : 16 q-rows (this wave) x 64 keys (exp2 domain, pre-scaled)
      f32x4 s[4] = {};
      __builtin_amdgcn_s_setprio(1);
#pragma unroll
      for (int kk = 0; kk < 4; ++kk) {
#pragma unroll
        for (int j = 0; j < 4; ++j) {
          int t = j * 16 + cl;
          int jp = (kk * 4 + quad) ^ (t & 7);
          bf16x8 bk = *(const bf16x8*)(cK + (t * 16 + jp) * 16);
          s[j] = __builtin_amdgcn_mfma_f32_16x16x32_bf16(qf[kk], bk, s[j], 0, 0, 0);
        }
      }
      __builtin_amdgcn_s_setprio(0);

      // causal mask + online softmax (deferred max, lane-local fast path)
      const bool need_mask = (kt == qt);
#pragma unroll
      for (int r = 0; r < 4; ++r) {
        int q_l = wave * 16 + quad * 4 + r;  // local q row (tile row)
        float mxl = -1e30f;
#pragma unroll
        for (int j = 0; j < 4; ++j) {
          float v = s[j][r];
          if (need_mask) {
            int t_l = j * 16 + cl;
            if (t_l > q_l) v = -1e30f;
            s[j][r] = v;
          }
          mxl = fmaxf(mxl, v);
        }
        // fast check on lane-local max; shfl reduce only in the rare branch.
        if (__any(mxl > m_i[r] + 6.f)) {
          float mx = mxl;
#pragma unroll
          for (int off = 1; off < 16; off <<= 1)
            mx = fmaxf(mx, __shfl_xor(mx, off));
          float m_new = fmaxf(m_i[r], mx);
          float alpha = exp2f(m_i[r] - m_new);
          m_i[r] = m_new;
          l_part[r] *= alpha;
#pragma unroll
          for (int jd = 0; jd < 8; ++jd)
            acc_o[jd][r] *= alpha;
        }
        float rs = 0.f;
#pragma unroll
        for (int j = 0; j < 4; ++j) {
          float p = exp2f(s[j][r] - m_i[r]);
          s[j][r] = p;
          rs += p;
        }
        l_part[r] += rs;  // per-lane partial; cross-lane reduce in epilogue
      }

      // write P swizzled into sP (wave-local rows -> no barrier needed)
#pragma unroll
      for (int j = 0; j < 4; ++j)
#pragma unroll
        for (int r = 0; r < 4; ++r) {
          int q = wave * 16 + quad * 4 + r;
          int swz = (q & 7) ^ (((q >> 3) & 1) << 1);
          int t = j * 16 + cl;
          int jp = (t >> 3) ^ swz;
          sP[(q * 8 + jp) * 8 + (t & 7)] = f2b(s[j][r]);
        }

      __syncthreads();  // B1: drains K[kt+1]+V[kt] (covered); sK[cur] reads done

      // O += P @ V (A from own-wave sP rows, B from sVT; both b128)
      __builtin_amdgcn_s_setprio(1);
#pragma unroll
      for (int kk2 = 0; kk2 < 2; ++kk2) {
        int q = wave * 16 + cl;
        int swz = (q & 7) ^ (((q >> 3) & 1) << 1);
        int jp = (kk2 * 4 + quad) ^ swz;
        bf16x8 ap = *(const bf16x8*)((const char*)sP + (q * 8 + jp) * 16);
#pragma unroll
        for (int jd = 0; jd < 8; ++jd) {
          int d = jd * 16 + cl;
          int jpv = (kk2 * 4 + quad) ^ (d & 7);
          bf16x8 bv = *(const bf16x8*)((const char*)sVT + (d * 8 + jpv) * 16);
          acc_o[jd] = __builtin_amdgcn_mfma_f32_16x16x32_bf16(ap, bv, acc_o[jd], 0, 0, 0);
        }
      }
      __builtin_amdgcn_s_setprio(0);

      __syncthreads();  // B2: pure sync — sVT reads done before next V issue
    }

    // epilogue: reduce l partials across the 16 row lanes, normalize, store
#pragma unroll
    for (int r = 0; r < 4; ++r) {
      float l = l_part[r];
#pragma unroll
      for (int off = 1; off < 16; off <<= 1)
        l += __shfl_xor(l, off);
      float inv = 1.f / l;
      int row = b * T + qt * 64 + wave * 16 + quad * 4 + r;
#pragma unroll
      for (int jd = 0; jd < 8; ++jd)
        Om[(size_t)row * ld + h * 128 + jd * 16 + cl] = f2b(acc_o[jd][r] * inv);
    }
  }
}

// ---------- launch ----------
extern "C" void kernel_launch(void* const* d_in, const int* in_sizes, int n_in,
                              void* d_out, int out_size, void* d_ws, size_t ws_size,
                              hipStream_t stream) {
  (void)in_sizes; (void)n_in; (void)out_size; (void)ws_size;
  const int B = 2, T = 2048, Dm = 2048, H = 16, Dh = 128, R = 512;
  const int M = B * T;  // 4096
  const float* x     = (const float*)d_in[0];
  const float* Wq    = (const float*)d_in[1];
  const float* Wdown = (const float*)d_in[2];
  const float* Wkup  = (const float*)d_in[3];
  const float* Wvup  = (const float*)d_in[4];
  const float* Wo    = (const float*)d_in[5];

  float* out  = (float*)d_out;                      // (B*T) x 2048 fp32
  float* cout = out + (size_t)M * Dm;               // (B*T) x 512  fp32

  unsigned short* ws  = (unsigned short*)d_ws;      // bf16 scratch
  unsigned short* WqT = ws;                         // 2048x2048 (stacked B rows 0..2047)
  unsigned short* WdT = WqT + (size_t)Dm * Dm;      // 512x2048  (stacked B rows 2048..2559)
  unsigned short* WoT = WdT + (size_t)R * Dm;       // 2048x2048
  unsigned short* WkT = WoT + (size_t)Dm * Dm;      // 2048x512
  unsigned short* WvT = WkT + (size_t)Dm * R;       // 2048x512
  unsigned short* xb  = WvT + (size_t)Dm * R;       // 4096x2048 (reused as AO)
  unsigned short* cb  = xb + (size_t)M * Dm;        // 4096x512
  unsigned short* Qb  = cb + (size_t)M * R;         // 4096x2048
  unsigned short* Kb  = Qb + (size_t)M * Dm;        // 4096x2048
  unsigned short* VT  = Kb + (size_t)M * Dm;        // 2048x4096 (V^T, d-major)
  unsigned short* AO  = xb;                         // alias: xb dead after Q-proj

  // softmax scale folded into Q: 1/sqrt(128) * log2(e)
  const float qscale = 0.08838834764831845f * 1.4426950408889634f;

  // input casts / weight transposes -> bf16 BT form
  cast_f32_bf16<<<(M * Dm) / 1024, 256, 0, stream>>>(x, xb, M * Dm);
  transpose_cast<<<dim3(32, 32), 256, 0, stream>>>(Wq, WqT, Dm, Dm);
  transpose_cast<<<dim3(8, 32), 256, 0, stream>>>(Wdown, WdT, Dm, R);
  transpose_cast<<<dim3(32, 32), 256, 0, stream>>>(Wo, WoT, Dm, Dm);
  transpose_cast<<<dim3(32, 8), 256, 0, stream>>>(Wkup, WkT, R, Dm);
  transpose_cast<<<dim3(32, 8), 256, 0, stream>>>(Wvup, WvT, R, Dm);

  // fused Q + c projection: grid (2560/128, 4096/128) = (20,32) = 640 blocks
  gemm_qc<<<dim3(20, 32), 256, 0, stream>>>(xb, WqT, Qb, cb, cout, Dm, qscale);

  // K projection: Kb[M,2048] = cb @ WkT^T
  gemm_bt<<<dim3(Dm / 128, M / 128), 256, 0, stream>>>(cb, WkT, Kb, nullptr, M, Dm, R, 1.f);
  // V^T directly: VT[2048,M] = WvT @ cb^T  (d-major layout for attn PV)
  gemm_bt<<<dim3(M / 128, Dm / 128), 256, 0, stream>>>(WvT, cb, VT, nullptr, Dm, M, R, 1.f);

  // causal attention: balanced pair {bx, 31-bx} per block
  mla_attn<<<dim3(T / 128, H, B), 256, 0, stream>>>(Qb, Kb, VT, AO, T);

  // output projection (fp32 out)
  gemm_bt<<<dim3(Dm / 128, M / 128), 256, 0, stream>>>(AO, WoT, nullptr, out, M, Dm, Dm, 1.f);
  (void)Dh; (void)H;
}

// Round 5
// 368.153 us; speedup vs baseline: 1.3998x; 1.0831x over previous
//
#include <hip/hip_runtime.h>

// ---------- common helpers ----------
typedef short bf16x8 __attribute__((ext_vector_type(8)));
typedef float f32x4 __attribute__((ext_vector_type(4)));

__device__ __forceinline__ void async16(const void* g, const void* l) {
  __builtin_amdgcn_global_load_lds(
      (const __attribute__((address_space(1))) unsigned int*)g,
      (__attribute__((address_space(3))) unsigned int*)(void*)(uintptr_t)l,
      16, 0, 0);
}

__device__ __forceinline__ unsigned short f2b(float f) {
  unsigned int u = __float_as_uint(f);
  u += 0x7fffu + ((u >> 16) & 1u);   // round-to-nearest-even
  return (unsigned short)(u >> 16);
}

// ---------- cast fp32 -> bf16, n % 1024 == 0 ----------
__global__ __launch_bounds__(256) void cast_f32_bf16(
    const float* __restrict__ in, unsigned short* __restrict__ out, int n) {
  int i = (blockIdx.x * 256 + threadIdx.x) * 4;
  if (i < n) {
    float4 v = *(const float4*)(in + i);
    ushort4 o;
    o.x = f2b(v.x); o.y = f2b(v.y); o.z = f2b(v.z); o.w = f2b(v.w);
    *(ushort4*)(out + i) = o;
  }
}

// ---------- transpose+cast: out_bf16[N][K] = in_f32[K][N], K,N multiples of 64 ----------
__global__ __launch_bounds__(256) void transpose_cast(
    const float* __restrict__ in, unsigned short* __restrict__ out,
    int K, int N) {
  __shared__ __align__(16) unsigned short tile[64][65];
  const int k0 = blockIdx.y * 64, n0 = blockIdx.x * 64;
  const int tid = threadIdx.x;
  const int r = tid >> 4, c4 = tid & 15;
#pragma unroll
  for (int p = 0; p < 4; ++p) {
    int row = p * 16 + r;
    float4 v = *(const float4*)(in + (size_t)(k0 + row) * N + n0 + c4 * 4);
    tile[c4 * 4 + 0][row] = f2b(v.x);
    tile[c4 * 4 + 1][row] = f2b(v.y);
    tile[c4 * 4 + 2][row] = f2b(v.z);
    tile[c4 * 4 + 3][row] = f2b(v.w);
  }
  __syncthreads();
#pragma unroll
  for (int p = 0; p < 4; ++p) {
    int nr = p * 16 + r;
    ushort4 o;
    o.x = tile[nr][c4 * 4 + 0];
    o.y = tile[nr][c4 * 4 + 1];
    o.z = tile[nr][c4 * 4 + 2];
    o.w = tile[nr][c4 * 4 + 3];
    *(ushort4*)(out + (size_t)(n0 + nr) * K + k0 + c4 * 4) = o;
  }
}

// ---------- GEMM v2: C[M,N] = A[M,K] @ BT[N,K]^T (bf16 in, fp32 accum) ----------
// M%128==0, N%128==0, K%64==0. 128x128 tile, BK=64, 4 waves 2x2.
// v2 vs v1 (Round-4 counters: MfmaUtil 16.5%, 1.57e7 LDS conflicts, ~half
// of each k-step = cold vmcnt(0) drain at the post-issue barrier):
//  * double-buffered LDS (64KB; residency already VGPR-capped at 2 blocks/CU
//    so no occupancy loss), ONE barrier per k-step: prefetch kt+1 issued
//    before compute of kt -> the barrier drain is covered by 32 MFMA + 16
//    ds_read (attn v6's proven pattern, +25% there).
//  * XOR-swizzled staging (attn's pattern): global source chunk
//    (lane&7)^(lane>>3), linear LDS dest; reads use chunk g^(row&7).
//    Kills the 16-way ds_read_b128 bank conflict (row stride 128B).
__global__ __launch_bounds__(256) void gemm_bt(
    const unsigned short* __restrict__ A, const unsigned short* __restrict__ BT,
    unsigned short* __restrict__ Cb, float* __restrict__ Cf, int M, int N, int K,
    float cscale) {
  __shared__ __align__(16) unsigned short sA[2][128 * 64];
  __shared__ __align__(16) unsigned short sB[2][128 * 64];
  const int tid = threadIdx.x;
  const int wave = tid >> 6, lane = tid & 63;
  const int quad = lane >> 4, cl = lane & 15;
  const int m0 = blockIdx.y * 128, n0 = blockIdx.x * 128;
  const int wm = (wave >> 1) * 64, wn = (wave & 1) * 64;
  (void)M;

  f32x4 acc[4][4] = {};

  // swizzled source: lane covers row (lane>>3) of its 8-row group, chunk
  // (lane&7)^(lane>>3). LDS dest stays linear (global_load_lds constraint).
  const int lr = lane >> 3;
  const int lc = (lane & 7) ^ lr;
  const unsigned short* gA = A + (size_t)(m0 + wave * 32 + lr) * K + lc * 8;
  const unsigned short* gB = BT + (size_t)(n0 + wave * 32 + lr) * K + lc * 8;
  const int nk = K >> 6;

  // prologue: stage k-tile 0 into buffer 0
#pragma unroll
  for (int r = 0; r < 4; ++r) {
    async16(gA + (size_t)r * 8 * K, (char*)sA[0] + (wave * 32 + r * 8) * 128);
    async16(gB + (size_t)r * 8 * K, (char*)sB[0] + (wave * 32 + r * 8) * 128);
  }
  __syncthreads();

  for (int kt = 0; kt < nk; ++kt) {
    const int cur = kt & 1;
    if (kt + 1 < nk) {
      const int k1 = (kt + 1) * 64;
#pragma unroll
      for (int r = 0; r < 4; ++r) {
        async16(gA + (size_t)r * 8 * K + k1,
                (char*)sA[cur ^ 1] + (wave * 32 + r * 8) * 128);
        async16(gB + (size_t)r * 8 * K + k1,
                (char*)sB[cur ^ 1] + (wave * 32 + r * 8) * 128);
      }
    }
    const char* cA = (const char*)sA[cur];
    const char* cB = (const char*)sB[cur];
#pragma unroll
    for (int kk = 0; kk < 2; ++kk) {
      const int g = kk * 4 + quad;  // global k-chunk this quad consumes
      bf16x8 af[4], bfr[4];
#pragma unroll
      for (int i = 0; i < 4; ++i) {
        int row = wm + i * 16 + cl;
        af[i] = *(const bf16x8*)(cA + row * 128 + (g ^ (cl & 7)) * 16);
      }
#pragma unroll
      for (int j = 0; j < 4; ++j) {
        int row = wn + j * 16 + cl;
        bfr[j] = *(const bf16x8*)(cB + row * 128 + (g ^ (cl & 7)) * 16);
      }
#pragma unroll
      for (int i = 0; i < 4; ++i)
#pragma unroll
        for (int j = 0; j < 4; ++j)
          acc[i][j] = __builtin_amdgcn_mfma_f32_16x16x32_bf16(af[i], bfr[j], acc[i][j], 0, 0, 0);
    }
    __syncthreads();  // drains prefetch (covered); buf[cur] reads complete
  }
#pragma unroll
  for (int i = 0; i < 4; ++i)
#pragma unroll
    for (int j = 0; j < 4; ++j)
#pragma unroll
      for (int r = 0; r < 4; ++r) {
        int row = m0 + wm + i * 16 + quad * 4 + r;
        int col = n0 + wn + j * 16 + cl;
        float v = acc[i][j][r];
        if (Cb) Cb[(size_t)row * N + col] = f2b(v * cscale);
        if (Cf) Cf[(size_t)row * N + col] = v;
      }
}

// ---------- fused Q+c projection GEMM (pipelined v2 body) ----------
// C[M,2560] = xb[M,2048] @ [WqT;WdT]^T. Epilogue splits: cols <2048 -> Qb
// (bf16, *qscale); cols >=2048 -> cb (bf16) + cout (fp32).
__global__ __launch_bounds__(256) void gemm_qc(
    const unsigned short* __restrict__ A, const unsigned short* __restrict__ BT,
    unsigned short* __restrict__ Qb, unsigned short* __restrict__ cb,
    float* __restrict__ cout, int K, float qscale) {
  __shared__ __align__(16) unsigned short sA[2][128 * 64];
  __shared__ __align__(16) unsigned short sB[2][128 * 64];
  const int tid = threadIdx.x;
  const int wave = tid >> 6, lane = tid & 63;
  const int quad = lane >> 4, cl = lane & 15;
  const int m0 = blockIdx.y * 128, n0 = blockIdx.x * 128;
  const int wm = (wave >> 1) * 64, wn = (wave & 1) * 64;

  f32x4 acc[4][4] = {};

  const int lr = lane >> 3;
  const int lc = (lane & 7) ^ lr;
  const unsigned short* gA = A + (size_t)(m0 + wave * 32 + lr) * K + lc * 8;
  const unsigned short* gB = BT + (size_t)(n0 + wave * 32 + lr) * K + lc * 8;
  const int nk = K >> 6;

#pragma unroll
  for (int r = 0; r < 4; ++r) {
    async16(gA + (size_t)r * 8 * K, (char*)sA[0] + (wave * 32 + r * 8) * 128);
    async16(gB + (size_t)r * 8 * K, (char*)sB[0] + (wave * 32 + r * 8) * 128);
  }
  __syncthreads();

  for (int kt = 0; kt < nk; ++kt) {
    const int cur = kt & 1;
    if (kt + 1 < nk) {
      const int k1 = (kt + 1) * 64;
#pragma unroll
      for (int r = 0; r < 4; ++r) {
        async16(gA + (size_t)r * 8 * K + k1,
                (char*)sA[cur ^ 1] + (wave * 32 + r * 8) * 128);
        async16(gB + (size_t)r * 8 * K + k1,
                (char*)sB[cur ^ 1] + (wave * 32 + r * 8) * 128);
      }
    }
    const char* cA = (const char*)sA[cur];
    const char* cB = (const char*)sB[cur];
#pragma unroll
    for (int kk = 0; kk < 2; ++kk) {
      const int g = kk * 4 + quad;
      bf16x8 af[4], bfr[4];
#pragma unroll
      for (int i = 0; i < 4; ++i) {
        int row = wm + i * 16 + cl;
        af[i] = *(const bf16x8*)(cA + row * 128 + (g ^ (cl & 7)) * 16);
      }
#pragma unroll
      for (int j = 0; j < 4; ++j) {
        int row = wn + j * 16 + cl;
        bfr[j] = *(const bf16x8*)(cB + row * 128 + (g ^ (cl & 7)) * 16);
      }
#pragma unroll
      for (int i = 0; i < 4; ++i)
#pragma unroll
        for (int j = 0; j < 4; ++j)
          acc[i][j] = __builtin_amdgcn_mfma_f32_16x16x32_bf16(af[i], bfr[j], acc[i][j], 0, 0, 0);
    }
    __syncthreads();
  }
  const bool qreg = (n0 < 2048);  // block-uniform (2048 % 128 == 0)
#pragma unroll
  for (int i = 0; i < 4; ++i)
#pragma unroll
    for (int j = 0; j < 4; ++j)
#pragma unroll
      for (int r = 0; r < 4; ++r) {
        int row = m0 + wm + i * 16 + quad * 4 + r;
        int col = n0 + wn + j * 16 + cl;
        float v = acc[i][j][r];
        if (qreg) {
          Qb[(size_t)row * 2048 + col] = f2b(v * qscale);
        } else {
          int c2 = col - 2048;
          cb[(size_t)row * 512 + c2] = f2b(v);
          cout[(size_t)row * 512 + c2] = v;
        }
      }
}

// ---------- flash-style causal attention, v7 (95.4us verified shell) ----------
// grid (16,16,2), 256 thr, balanced pair {bx, 31-bx} (33 k-tiles/block),
// K double-buffered (LDS 56KB, 2 blocks/CU), V staged under QK^T+softmax
// cover, B1 drains hidden, B2 pure sync; setprio(1) around MFMA clusters.
__global__ __launch_bounds__(256) void mla_attn(
    const unsigned short* __restrict__ Qm, const unsigned short* __restrict__ Km,
    const unsigned short* __restrict__ Vt, unsigned short* __restrict__ Om, int T) {
  const int ld = 2048;
  const int ldv = 4096;  // B*T
  __shared__ __align__(16) unsigned short sK[2][64 * 128];  // [t][d] xor-swizzled
  __shared__ __align__(16) unsigned short sVT[128 * 64];    // [d][t] xor-swizzled
  __shared__ __align__(16) unsigned short sP[64 * 64];      // [q][t] swz(q)-swizzled
  const int h = blockIdx.y, b = blockIdx.z;
  const int tid = threadIdx.x, wave = tid >> 6, lane = tid & 63;
  const int quad = lane >> 4, cl = lane & 15;
  const int nq = T / 64;  // 32

  for (int phase = 0; phase < 2; ++phase) {
    const int qt = phase ? (nq - 1 - blockIdx.x) : blockIdx.x;

    // Q A-fragments in registers (pre-scaled by 1/sqrt(Dh)*log2e in Q-GEMM)
    bf16x8 qf[4];
    {
      const unsigned short* Qg =
          Qm + (size_t)(b * T + qt * 64 + wave * 16 + cl) * ld + h * 128 + quad * 8;
#pragma unroll
      for (int kk = 0; kk < 4; ++kk)
        qf[kk] = *(const bf16x8*)(Qg + kk * 32);
    }

    float m_i[4], l_part[4];
    f32x4 acc_o[8] = {};
#pragma unroll
    for (int r = 0; r < 4; ++r) { m_i[r] = -1e30f; l_part[r] = 0.f; }

    const unsigned short* Kg0 = Km + (size_t)(b * T) * ld + h * 128;
    const unsigned short* Vg0 = Vt + (size_t)(h * 128) * ldv + (size_t)b * T;

    // prologue: stage K[0] into buffer 0
#pragma unroll
    for (int r = 0; r < 4; ++r) {
      int c0 = r * 256 + wave * 64;
      int c = c0 + lane;
      int row = c >> 4, j = (c & 15) ^ (row & 7);
      async16(Kg0 + (size_t)row * ld + j * 8, (char*)sK[0] + c0 * 16);
    }
    __syncthreads();  // drain K[0] (and phase's Q register loads)

    for (int kt = 0; kt <= qt; ++kt) {
      const int cur = kt & 1;
      const char* cK = (const char*)sK[cur];

      // issue next K tile into the other buffer (overlaps QK^T on sK[cur])
      if (kt < qt) {
        const unsigned short* Kg = Kg0 + (size_t)(kt + 1) * 64 * ld;
        char* dK = (char*)sK[cur ^ 1];
#pragma unroll
        for (int r = 0; r < 4; ++r) {
          int c0 = r * 256 + wave * 64;
          int c = c0 + lane;
          int row = c >> 4, j = (c & 15) ^ (row & 7);
          async16(Kg + (size_t)row * ld + j * 8, dK + c0 * 16);
        }
      }
      // issue this tile's V (prev PV reads of sVT completed at B2)
      {
        const unsigned short* Vg = Vg0 + kt * 64;
#pragma unroll
        for (int r = 0; r < 4; ++r) {
          int c0 = r * 256 + wave * 64;
          int c = c0 + lane;
          int d = c >> 3, jv = (c & 7) ^ (d & 7);
          async16(Vg + (size_t)d * ldv + jv * 8, (char*)sVT + c0 * 16);
        }
      }

      // S = Q @ K^T : 16 q-rows (this wave) x 64 keys (exp2 domain, pre-scaled)
      f32x4 s[4] = {};
      __builtin_amdgcn_s_setprio(1);
#pragma unroll
      for (int kk = 0; kk < 4; ++kk) {
#pragma unroll
        for (int j = 0; j < 4; ++j) {
          int t = j * 16 + cl;
          int jp = (kk * 4 + quad) ^ (t & 7);
          bf16x8 bk = *(const bf16x8*)(cK + (t * 16 + jp) * 16);
          s[j] = __builtin_amdgcn_mfma_f32_16x16x32_bf16(qf[kk], bk, s[j], 0, 0, 0);
        }
      }
      __builtin_amdgcn_s_setprio(0);

      // causal mask + online softmax (deferred max, lane-local fast path)
      const bool need_mask = (kt == qt);
#pragma unroll
      for (int r = 0; r < 4; ++r) {
        int q_l = wave * 16 + quad * 4 + r;  // local q row (tile row)
        float mxl = -1e30f;
#pragma unroll
        for (int j = 0; j < 4; ++j) {
          float v = s[j][r];
          if (need_mask) {
            int t_l = j * 16 + cl;
            if (t_l > q_l) v = -1e30f;
            s[j][r] = v;
          }
          mxl = fmaxf(mxl, v);
        }
        // fast check on lane-local max; shfl reduce only in the rare branch.
        if (__any(mxl > m_i[r] + 6.f)) {
          float mx = mxl;
#pragma unroll
          for (int off = 1; off < 16; off <<= 1)
            mx = fmaxf(mx, __shfl_xor(mx, off));
          float m_new = fmaxf(m_i[r], mx);
          float alpha = exp2f(m_i[r] - m_new);
          m_i[r] = m_new;
          l_part[r] *= alpha;
#pragma unroll
          for (int jd = 0; jd < 8; ++jd)
            acc_o[jd][r] *= alpha;
        }
        float rs = 0.f;
#pragma unroll
        for (int j = 0; j < 4; ++j) {
          float p = exp2f(s[j][r] - m_i[r]);
          s[j][r] = p;
          rs += p;
        }
        l_part[r] += rs;  // per-lane partial; cross-lane reduce in epilogue
      }

      // write P swizzled into sP (wave-local rows -> no barrier needed)
#pragma unroll
      for (int j = 0; j < 4; ++j)
#pragma unroll
        for (int r = 0; r < 4; ++r) {
          int q = wave * 16 + quad * 4 + r;
          int swz = (q & 7) ^ (((q >> 3) & 1) << 1);
          int t = j * 16 + cl;
          int jp = (t >> 3) ^ swz;
          sP[(q * 8 + jp) * 8 + (t & 7)] = f2b(s[j][r]);
        }

      __syncthreads();  // B1: drains K[kt+1]+V[kt] (covered); sK[cur] reads done

      // O += P @ V (A from own-wave sP rows, B from sVT; both b128)
      __builtin_amdgcn_s_setprio(1);
#pragma unroll
      for (int kk2 = 0; kk2 < 2; ++kk2) {
        int q = wave * 16 + cl;
        int swz = (q & 7) ^ (((q >> 3) & 1) << 1);
        int jp = (kk2 * 4 + quad) ^ swz;
        bf16x8 ap = *(const bf16x8*)((const char*)sP + (q * 8 + jp) * 16);
#pragma unroll
        for (int jd = 0; jd < 8; ++jd) {
          int d = jd * 16 + cl;
          int jpv = (kk2 * 4 + quad) ^ (d & 7);
          bf16x8 bv = *(const bf16x8*)((const char*)sVT + (d * 8 + jpv) * 16);
          acc_o[jd] = __builtin_amdgcn_mfma_f32_16x16x32_bf16(ap, bv, acc_o[jd], 0, 0, 0);
        }
      }
      __builtin_amdgcn_s_setprio(0);

      __syncthreads();  // B2: pure sync — sVT reads done before next V issue
    }

    // epilogue: reduce l partials across the 16 row lanes, normalize, store
#pragma unroll
    for (int r = 0; r < 4; ++r) {
      float l = l_part[r];
#pragma unroll
      for (int off = 1; off < 16; off <<= 1)
        l += __shfl_xor(l, off);
      float inv = 1.f / l;
      int row = b * T + qt * 64 + wave * 16 + quad * 4 + r;
#pragma unroll
      for (int jd = 0; jd < 8; ++jd)
        Om[(size_t)row * ld + h * 128 + jd * 16 + cl] = f2b(acc_o[jd][r] * inv);
    }
  }
}

// ---------- launch ----------
extern "C" void kernel_launch(void* const* d_in, const int* in_sizes, int n_in,
                              void* d_out, int out_size, void* d_ws, size_t ws_size,
                              hipStream_t stream) {
  (void)in_sizes; (void)n_in; (void)out_size; (void)ws_size;
  const int B = 2, T = 2048, Dm = 2048, H = 16, Dh = 128, R = 512;
  const int M = B * T;  // 4096
  const float* x     = (const float*)d_in[0];
  const float* Wq    = (const float*)d_in[1];
  const float* Wdown = (const float*)d_in[2];
  const float* Wkup  = (const float*)d_in[3];
  const float* Wvup  = (const float*)d_in[4];
  const float* Wo    = (const float*)d_in[5];

  float* out  = (float*)d_out;                      // (B*T) x 2048 fp32
  float* cout = out + (size_t)M * Dm;               // (B*T) x 512  fp32

  unsigned short* ws  = (unsigned short*)d_ws;      // bf16 scratch
  unsigned short* WqT = ws;                         // 2048x2048 (stacked B rows 0..2047)
  unsigned short* WdT = WqT + (size_t)Dm * Dm;      // 512x2048  (stacked B rows 2048..2559)
  unsigned short* WoT = WdT + (size_t)R * Dm;       // 2048x2048
  unsigned short* WkT = WoT + (size_t)Dm * Dm;      // 2048x512
  unsigned short* WvT = WkT + (size_t)Dm * R;       // 2048x512
  unsigned short* xb  = WvT + (size_t)Dm * R;       // 4096x2048 (reused as AO)
  unsigned short* cb  = xb + (size_t)M * Dm;        // 4096x512
  unsigned short* Qb  = cb + (size_t)M * R;         // 4096x2048
  unsigned short* Kb  = Qb + (size_t)M * Dm;        // 4096x2048
  unsigned short* VT  = Kb + (size_t)M * Dm;        // 2048x4096 (V^T, d-major)
  unsigned short* AO  = xb;                         // alias: xb dead after Q-proj

  // softmax scale folded into Q: 1/sqrt(128) * log2(e)
  const float qscale = 0.08838834764831845f * 1.4426950408889634f;

  // input casts / weight transposes -> bf16 BT form
  cast_f32_bf16<<<(M * Dm) / 1024, 256, 0, stream>>>(x, xb, M * Dm);
  transpose_cast<<<dim3(32, 32), 256, 0, stream>>>(Wq, WqT, Dm, Dm);
  transpose_cast<<<dim3(8, 32), 256, 0, stream>>>(Wdown, WdT, Dm, R);
  transpose_cast<<<dim3(32, 32), 256, 0, stream>>>(Wo, WoT, Dm, Dm);
  transpose_cast<<<dim3(32, 8), 256, 0, stream>>>(Wkup, WkT, R, Dm);
  transpose_cast<<<dim3(32, 8), 256, 0, stream>>>(Wvup, WvT, R, Dm);

  // fused Q + c projection: grid (2560/128, 4096/128) = (20,32) = 640 blocks
  gemm_qc<<<dim3(20, 32), 256, 0, stream>>>(xb, WqT, Qb, cb, cout, Dm, qscale);

  // K projection: Kb[M,2048] = cb @ WkT^T
  gemm_bt<<<dim3(Dm / 128, M / 128), 256, 0, stream>>>(cb, WkT, Kb, nullptr, M, Dm, R, 1.f);
  // V^T directly: VT[2048,M] = WvT @ cb^T  (d-major layout for attn PV)
  gemm_bt<<<dim3(M / 128, Dm / 128), 256, 0, stream>>>(WvT, cb, VT, nullptr, Dm, M, R, 1.f);

  // causal attention: balanced pair {bx, 31-bx} per block
  mla_attn<<<dim3(T / 128, H, B), 256, 0, stream>>>(Qb, Kb, VT, AO, T);

  // output projection (fp32 out)
  gemm_bt<<<dim3(Dm / 128, M / 128), 256, 0, stream>>>(AO, WoT, nullptr, out, M, Dm, Dm, 1.f);
  (void)Dh; (void)H;
}